// Round 10
// baseline (329.541 us; speedup 1.0000x reference)
//
#include <hip/hip_runtime.h>
#include <hip/hip_bf16.h>
#include <hip/hip_fp16.h>
#include <math.h>

#define DI 1536
#define DM 768
#define DS 16
#define BB 2
#define LL 2048
#define ML (BB*LL)          /* 4096 rows */
#define NCHUNK 32
#define CLEN (LL/NCHUNK)    /* 64 */
#define NDT 1600            /* dt-GEMM tiled N: 1536 dt + 32 BC + 32 discard */

using short8  = __attribute__((ext_vector_type(8))) short;
using floatx4 = __attribute__((ext_vector_type(4))) float;

__device__ __forceinline__ float bf2f(__hip_bfloat16 v) { return __bfloat162float(v); }

// async global->LDS copy, 16 B per lane (LDS dest lane-contiguous).
__device__ __forceinline__ void async_cp16(const void* g, void* l)
{
    __builtin_amdgcn_global_load_lds(
        (const __attribute__((address_space(1))) unsigned int*)g,
        (__attribute__((address_space(3))) unsigned int*)l,
        16, 0, 0);
}

// ---------------------------------------------------------------------------
__global__ __launch_bounds__(256) void cvt_f32_bf16(
    const float* __restrict__ s, __hip_bfloat16* __restrict__ d)
{
    int i = (blockIdx.x * 256 + threadIdx.x) * 4;
    float4 v = *reinterpret_cast<const float4*>(s + i);
    __hip_bfloat16 o[4];
    o[0] = __float2bfloat16(v.x); o[1] = __float2bfloat16(v.y);
    o[2] = __float2bfloat16(v.z); o[3] = __float2bfloat16(v.w);
    *reinterpret_cast<uint2*>(d + i) = *reinterpret_cast<const uint2*>(o);
}

// ---------------------------------------------------------------------------
// Transpose f32 (R x C) -> bf16 (C x R). Dims multiples of 32.
// ---------------------------------------------------------------------------
__global__ __launch_bounds__(256) void transpose_f32_bf16(
    const float* __restrict__ src, __hip_bfloat16* __restrict__ dst,
    int R, int C)
{
    __shared__ __hip_bfloat16 tile[32][34];
    int c0 = blockIdx.x * 32, r0 = blockIdx.y * 32;
    int lx = threadIdx.x & 31, ly = threadIdx.x >> 5;
#pragma unroll
    for (int i = 0; i < 4; ++i)
        tile[ly + 8*i][lx] = __float2bfloat16(src[(size_t)(r0 + ly + 8*i) * C + c0 + lx]);
    __syncthreads();
#pragma unroll
    for (int i = 0; i < 4; ++i)
        dst[(size_t)(c0 + ly + 8*i) * R + r0 + lx] = tile[lx][ly + 8*i];
}

// ---------------------------------------------------------------------------
// MFMA bf16 GEMM, 128x128 tile, BK=64 as two BK=32 panels (measured win for
// the 128x128 shape, round 9).  B given TRANSPOSED as BT[N,K].
// EPI 0: bf16 -> C0 (stride N).  EPI 2: f32 -> C0/C1/C2 by blockIdx.z.
// ---------------------------------------------------------------------------
template <int EPI, int SK>
__global__ __launch_bounds__(256) void gemm_bf16(
    const __hip_bfloat16* __restrict__ A,
    const __hip_bfloat16* __restrict__ BT,
    void* __restrict__ C0, void* __restrict__ C1, void* __restrict__ C2,
    int M, int N, int K)
{
    __shared__ __hip_bfloat16 As[2][128][32];   // per panel: byte off = tid*16
    __shared__ __hip_bfloat16 Bs[2][128][32];

    int tid  = threadIdx.x;
    int wave = tid >> 6, lane = tid & 63;
    int quad = lane >> 4, lr = lane & 15;
    int wm = (wave >> 1) * 64, wn = (wave & 1) * 64;
    int bm = blockIdx.x * 128, bn = blockIdx.y * 128;

    floatx4 acc[4][4];
#pragma unroll
    for (int i = 0; i < 4; ++i)
#pragma unroll
        for (int j = 0; j < 4; ++j)
            acc[i][j] = (floatx4){0.f, 0.f, 0.f, 0.f};

    int sr = tid >> 2;              // 0..63
    int sc = (tid & 3) * 8;         // 0,8,16,24

    int Klen  = K / SK;
    int kbase = (SK > 1) ? (int)blockIdx.z * Klen : 0;

    const __hip_bfloat16* gA0 = A  + (size_t)(bm + sr)      * K + sc;
    const __hip_bfloat16* gA1 = A  + (size_t)(bm + sr + 64) * K + sc;
    const __hip_bfloat16* gB0 = BT + (size_t)(bn + sr)      * K + sc;
    const __hip_bfloat16* gB1 = BT + (size_t)(bn + sr + 64) * K + sc;

    for (int k0 = kbase; k0 < kbase + Klen; k0 += 64) {
        async_cp16(gA0 + k0,      &As[0][sr][sc]);
        async_cp16(gA0 + k0 + 32, &As[1][sr][sc]);
        async_cp16(gA1 + k0,      &As[0][sr + 64][sc]);
        async_cp16(gA1 + k0 + 32, &As[1][sr + 64][sc]);
        async_cp16(gB0 + k0,      &Bs[0][sr][sc]);
        async_cp16(gB0 + k0 + 32, &Bs[1][sr][sc]);
        async_cp16(gB1 + k0,      &Bs[0][sr + 64][sc]);
        async_cp16(gB1 + k0 + 32, &Bs[1][sr + 64][sc]);
        __syncthreads();

#pragma unroll
        for (int p = 0; p < 2; ++p) {
            short8 afrag[4], bfrag[4];
#pragma unroll
            for (int i = 0; i < 4; ++i)
                afrag[i] = *reinterpret_cast<const short8*>(&As[p][wm + i*16 + lr][quad*8]);
#pragma unroll
            for (int j = 0; j < 4; ++j)
                bfrag[j] = *reinterpret_cast<const short8*>(&Bs[p][wn + j*16 + lr][quad*8]);
#pragma unroll
            for (int i = 0; i < 4; ++i)
#pragma unroll
                for (int j = 0; j < 4; ++j)
                    acc[i][j] = __builtin_amdgcn_mfma_f32_16x16x32_bf16(
                        afrag[i], bfrag[j], acc[i][j], 0, 0, 0);
        }
        __syncthreads();
    }

    float* skOut = nullptr;
    if (EPI == 2)
        skOut = (SK == 1) ? (float*)C0
              : (blockIdx.z == 0 ? (float*)C0 : blockIdx.z == 1 ? (float*)C1 : (float*)C2);

    // epilogue: within 16x16 tile, row = quad*4 + rr, col = lr
#pragma unroll
    for (int i = 0; i < 4; ++i) {
#pragma unroll
        for (int j = 0; j < 4; ++j) {
            int r0 = bm + wm + i*16 + quad*4;
            int c  = bn + wn + j*16 + lr;
#pragma unroll
            for (int rr = 0; rr < 4; ++rr) {
                float v = acc[i][j][rr];
                if (EPI == 0) {
                    ((__hip_bfloat16*)C0)[(size_t)(r0 + rr) * N + c] = __float2bfloat16(v);
                } else {
                    skOut[(size_t)(r0 + rr) * N + c] = v;
                }
            }
        }
    }
}

// ---------------------------------------------------------------------------
// dt-GEMM, 128x64 tile, BK=32 (measured best for this shape — round 8:
// 66.6 us; BK=64 regressed to 87 us via 25% grid-tail amplification).
// B^T = [W_dt^T ; W_x^T ; pad] (NDT x K).  cols<DI: softplus(+bias) -> f16 dt;
// cols DI..DI+31: f32 -> BC; cols >= DI+32: discard.
// ---------------------------------------------------------------------------
__global__ __launch_bounds__(256) void gemm_dt(
    const __hip_bfloat16* __restrict__ A,
    const __hip_bfloat16* __restrict__ BT,
    __half* __restrict__ dtb, float* __restrict__ BC,
    const float* __restrict__ bias,
    int M, int K)
{
    __shared__ __hip_bfloat16 As[128][32];   // 8 KB, byte off = tid*16
    __shared__ __hip_bfloat16 Bs[64][32];    // 4 KB

    int tid  = threadIdx.x;
    int wave = tid >> 6, lane = tid & 63;
    int quad = lane >> 4, lr = lane & 15;
    int wm = (wave >> 1) * 64, wn = (wave & 1) * 32;
    int bm = blockIdx.x * 128, bn = blockIdx.y * 64;

    floatx4 acc[4][2];
#pragma unroll
    for (int i = 0; i < 4; ++i)
#pragma unroll
        for (int j = 0; j < 2; ++j)
            acc[i][j] = (floatx4){0.f, 0.f, 0.f, 0.f};

    int sr = tid >> 2;              // 0..63
    int sc = (tid & 3) * 8;

    const __hip_bfloat16* gA0 = A  + (size_t)(bm + sr)      * K + sc;
    const __hip_bfloat16* gA1 = A  + (size_t)(bm + sr + 64) * K + sc;
    const __hip_bfloat16* gB0 = BT + (size_t)(bn + sr)      * K + sc;
    __hip_bfloat16* lA0 = &As[sr][sc];
    __hip_bfloat16* lA1 = &As[sr + 64][sc];
    __hip_bfloat16* lB0 = &Bs[sr][sc];

    for (int k0 = 0; k0 < K; k0 += 32) {
        async_cp16(gA0 + k0, lA0);
        async_cp16(gA1 + k0, lA1);
        async_cp16(gB0 + k0, lB0);
        __syncthreads();

        short8 afrag[4], bfrag[2];
#pragma unroll
        for (int i = 0; i < 4; ++i)
            afrag[i] = *reinterpret_cast<const short8*>(&As[wm + i*16 + lr][quad*8]);
#pragma unroll
        for (int j = 0; j < 2; ++j)
            bfrag[j] = *reinterpret_cast<const short8*>(&Bs[wn + j*16 + lr][quad*8]);
#pragma unroll
        for (int i = 0; i < 4; ++i)
#pragma unroll
            for (int j = 0; j < 2; ++j)
                acc[i][j] = __builtin_amdgcn_mfma_f32_16x16x32_bf16(
                    afrag[i], bfrag[j], acc[i][j], 0, 0, 0);
        __syncthreads();
    }

#pragma unroll
    for (int i = 0; i < 4; ++i) {
#pragma unroll
        for (int j = 0; j < 2; ++j) {
            int r0 = bm + wm + i*16 + quad*4;
            int c  = bn + wn + j*16 + lr;
#pragma unroll
            for (int rr = 0; rr < 4; ++rr) {
                float v = acc[i][j][rr];
                if (c < DI) {
                    v += bias[c];
                    float sp = (v > 20.f) ? v : log1pf(__expf(v));
                    dtb[(size_t)(r0 + rr) * DI + c] = __float2half(sp);
                } else if (c < DI + 32) {
                    BC[(size_t)(r0 + rr) * 32 + (c - DI)] = v;
                } // else discard
            }
        }
    }
}

// ---------------------------------------------------------------------------
// d += p1 + p2 (split-K reduce), float4 per thread.
// ---------------------------------------------------------------------------
__global__ __launch_bounds__(256) void add3(
    float* __restrict__ d, const float* __restrict__ p1, const float* __restrict__ p2)
{
    int i = (blockIdx.x * 256 + threadIdx.x) * 4;
    float4 a = *reinterpret_cast<float4*>(d + i);
    float4 b = *reinterpret_cast<const float4*>(p1 + i);
    float4 c = *reinterpret_cast<const float4*>(p2 + i);
    a.x += b.x + c.x; a.y += b.y + c.y; a.z += b.z + c.z; a.w += b.w + c.w;
    *reinterpret_cast<float4*>(d + i) = a;
}

// ---------------------------------------------------------------------------
// Depthwise causal conv (k=4) + bias + SiLU, 8 channels/thread (16B vectors).
// ---------------------------------------------------------------------------
__global__ __launch_bounds__(256) void conv_silu(
    const __hip_bfloat16* __restrict__ xz,
    const float* __restrict__ Wc,
    const float* __restrict__ bc,
    __hip_bfloat16* __restrict__ xc)
{
    int idx = blockIdx.x * 256 + threadIdx.x;      // over ML*DI/8
    int d = (idx % (DI/8)) * 8;
    int m = idx / (DI/8);                          // m = b*LL + t
    int t = m % LL;
    float acc[8];
#pragma unroll
    for (int h = 0; h < 2; ++h) {
        float4 b4 = *reinterpret_cast<const float4*>(bc + d + h*4);
        acc[h*4+0] = b4.x; acc[h*4+1] = b4.y; acc[h*4+2] = b4.z; acc[h*4+3] = b4.w;
    }
    float4 w[8];
#pragma unroll
    for (int l = 0; l < 8; ++l)
        w[l] = *reinterpret_cast<const float4*>(Wc + (size_t)(d + l) * 4);
#pragma unroll
    for (int j = 0; j < 4; ++j) {
        if (t - 3 + j >= 0) {
            uint4 raw = *reinterpret_cast<const uint4*>(xz + (size_t)(m - 3 + j) * (2*DI) + d);
            __hip_bfloat16 xv[8];
            *reinterpret_cast<uint4*>(xv) = raw;
#pragma unroll
            for (int l = 0; l < 8; ++l)
                acc[l] += bf2f(xv[l]) * ((const float*)&w[l])[j];
        }
    }
    __hip_bfloat16 o[8];
#pragma unroll
    for (int l = 0; l < 8; ++l) {
        float s = acc[l] / (1.f + __expf(-acc[l]));
        o[l] = __float2bfloat16(s);
    }
    *reinterpret_cast<uint4*>(xc + (size_t)m * DI + d) = *reinterpret_cast<const uint4*>(o);
}

// ---------------------------------------------------------------------------
// Chunked scan, thread-per-(d, 4 states).  32 chunks x 64 steps.
// ---------------------------------------------------------------------------
__global__ __launch_bounds__(256) void scan_phaseA(
    const __half* __restrict__ dt, const __hip_bfloat16* __restrict__ xc,
    const float* __restrict__ BC, const float* __restrict__ A_log,
    __half* __restrict__ aprod, __half* __restrict__ hend)
{
    int idx = blockIdx.x * 256 + threadIdx.x;   // over DI*4 = 6144
    int q = idx & 3, d = idx >> 2;
    int c = blockIdx.y, b = blockIdx.z;
    float A4[4], h[4], ap[4];
#pragma unroll
    for (int j = 0; j < 4; ++j) {
        A4[j] = -__expf(A_log[d*DS + q*4 + j]);
        h[j] = 0.f; ap[j] = 1.f;
    }
    int t0 = c * CLEN;
    for (int t = t0; t < t0 + CLEN; ++t) {
        size_t row = (size_t)b * LL + t;
        float dtv = __half2float(dt[row * DI + d]);
        float xcv = bf2f(xc[row * DI + d]);
        float4 B4 = *reinterpret_cast<const float4*>(BC + row * 32 + q*4);
        float dtx = dtv * xcv;
#pragma unroll
        for (int j = 0; j < 4; ++j) {
            float dA = __expf(dtv * A4[j]);
            h[j]  = dA * h[j] + ((const float*)&B4)[j] * dtx;
            ap[j] *= dA;
        }
    }
    size_t o = (((size_t)b * NCHUNK + c) * DI + d) * DS + q*4;
    __half oa[4], oh[4];
#pragma unroll
    for (int j = 0; j < 4; ++j) { oa[j] = __float2half(ap[j]); oh[j] = __float2half(h[j]); }
    *reinterpret_cast<uint2*>(aprod + o) = *reinterpret_cast<const uint2*>(oa);
    *reinterpret_cast<uint2*>(hend  + o) = *reinterpret_cast<const uint2*>(oh);
}

__global__ __launch_bounds__(256) void scan_phaseB(
    const __half* __restrict__ aprod, __half* __restrict__ hse)
{
    int idx = blockIdx.x * 256 + threadIdx.x;   // over BB*DI*DS
    int b = idx / (DI*DS);
    int dn = idx % (DI*DS);
    float H = 0.f;
#pragma unroll
    for (int c = 0; c < NCHUNK; ++c) {
        size_t o = ((size_t)b * NCHUNK + c) * (DI*DS) + dn;
        float a  = __half2float(aprod[o]);
        float he = __half2float(hse[o]);
        hse[o] = __float2half(H);          // becomes hstart for chunk c
        H = a * H + he;
    }
}

__global__ __launch_bounds__(256) void scan_phaseC(
    const __half* __restrict__ dt, const __hip_bfloat16* __restrict__ xz,
    const float* __restrict__ BC, const float* __restrict__ A_log,
    const float* __restrict__ Dv, const __half* __restrict__ hstart,
    __hip_bfloat16* __restrict__ xc_y /* xc in, y out (in place) */)
{
    int idx = blockIdx.x * 256 + threadIdx.x;   // over DI*4 = 6144
    int q = idx & 3, d = idx >> 2;
    int c = blockIdx.y, b = blockIdx.z;
    float A4[4], h[4];
#pragma unroll
    for (int j = 0; j < 4; ++j)
        A4[j] = -__expf(A_log[d*DS + q*4 + j]);
    float Dd = Dv[d];
    size_t o = (((size_t)b * NCHUNK + c) * DI + d) * DS + q*4;
    {
        uint2 tmp = *reinterpret_cast<const uint2*>(hstart + o);
        const __half* hp = reinterpret_cast<const __half*>(&tmp);
#pragma unroll
        for (int j = 0; j < 4; ++j) h[j] = __half2float(hp[j]);
    }
    int t0 = c * CLEN;
    for (int t = t0; t < t0 + CLEN; ++t) {
        size_t row = (size_t)b * LL + t;
        float dtv = __half2float(dt[row * DI + d]);
        float xcv = bf2f(xc_y[row * DI + d]);       // read BEFORE the masked write
        float zv  = bf2f(xz[row * (2*DI) + DI + d]);
        float4 B4 = *reinterpret_cast<const float4*>(BC + row * 32 + q*4);
        float4 C4 = *reinterpret_cast<const float4*>(BC + row * 32 + 16 + q*4);
        float dtx = dtv * xcv;
        float ys = 0.f;
#pragma unroll
        for (int j = 0; j < 4; ++j) {
            float dA = __expf(dtv * A4[j]);
            h[j] = dA * h[j] + ((const float*)&B4)[j] * dtx;
            ys = fmaf(h[j], ((const float*)&C4)[j], ys);
        }
        ys += __shfl_xor(ys, 1);
        ys += __shfl_xor(ys, 2);
        if (q == 0) {
            float sig = 1.f / (1.f + __expf(-zv));
            float out = (ys + xcv * Dd) * (zv * sig);
            xc_y[row * DI + d] = __float2bfloat16(out);
        }
    }
}

// ---------------------------------------------------------------------------
extern "C" void kernel_launch(void* const* d_in, const int* in_sizes, int n_in,
                              void* d_out, int out_size, void* d_ws, size_t ws_size,
                              hipStream_t stream)
{
    const float* x      = (const float*)d_in[0];
    const float* W_in   = (const float*)d_in[1];
    const float* W_conv = (const float*)d_in[2];
    const float* b_conv = (const float*)d_in[3];
    const float* W_x    = (const float*)d_in[4];
    const float* W_dt   = (const float*)d_in[5];
    const float* b_dt   = (const float*)d_in[6];
    const float* A_log  = (const float*)d_in[7];
    const float* Dvec   = (const float*)d_in[8];
    const float* W_out  = (const float*)d_in[9];

    // ---- workspace layout (62.26 MiB, explicit lifetime reuse) ----
    uint8_t* ws = (uint8_t*)d_ws;
    __hip_bfloat16* xz     = (__hip_bfloat16*)(ws);               // 25,165,824 [G1..phaseC]
    float*          p1     = (float*)(ws);                        // 12,582,912 [G4..add3] (over xz)
    float*          p2     = (float*)(ws + 12582912);             // 12,582,912 [G4..add3] (over xz)
    __hip_bfloat16* winT   = (__hip_bfloat16*)(ws + 25165824);    //  4,718,592 [T1..G1]
    __half*         aprod  = (__half*)(ws + 25165824);            //  3,145,728 [phA..phB] (over winT)
    __half*         hse    = (__half*)(ws + 28311552);            //  3,145,728 [phA..phC] (over winT)
    __hip_bfloat16* wcombT = (__hip_bfloat16*)(ws + 31457280);    //  4,915,200 [T2..dtG]  (NDT x DI; rows 1568+ unwritten)
    __hip_bfloat16* woutT  = (__hip_bfloat16*)(ws + 31457280);    //  2,359,296 [T3..G4]   (over wcombT, after dtG)
    __hip_bfloat16* xcb    = (__hip_bfloat16*)(ws + 36569088);    // 12,582,912 [conv..G4], y in place
    __half*         dtb    = (__half*)(ws + 49152000);            // 12,582,912 [dtG..phaseC]
    __hip_bfloat16* xbf    = (__hip_bfloat16*)(ws + 49152000);    //  6,291,456 [cvt..G1]  (over dtb)
    float*          BC     = (float*)(ws + 61734912);             //    524,288 [dtG..phaseC]
    // end: 62,259,200 bytes

    // input conversions / weight transposes (f32 -> bf16, B^T layout)
    cvt_f32_bf16<<<(ML*DM)/1024, 256, 0, stream>>>(x, xbf);
    transpose_f32_bf16<<<dim3(2*DI/32, DM/32), 256, 0, stream>>>(W_in, winT, DM, 2*DI);
    transpose_f32_bf16<<<dim3(DI/32,   DI/32), 256, 0, stream>>>(W_dt, wcombT, DI, DI);
    transpose_f32_bf16<<<dim3(1,       DI/32), 256, 0, stream>>>(W_x,  wcombT + (size_t)DI*DI, DI, 32);

    // GEMM1: xz = x @ W_in     (4096 x 3072 x 768), BK=64
    gemm_bf16<0,1><<<dim3(ML/128, (2*DI)/128), 256, 0, stream>>>(
        xbf, winT, xz, nullptr, nullptr, ML, 2*DI, DM);

    // conv + SiLU -> xc
    conv_silu<<<(ML*DI/8)/256, 256, 0, stream>>>(xz, W_conv, b_conv, xcb);

    // fused: dt = softplus(xc @ W_dt + b_dt) -> f16  AND  BC = xc @ W_x -> f32
    // 128x64 tile, BK=32 (measured best, round 8)
    gemm_dt<<<dim3(ML/128, NDT/64), 256, 0, stream>>>(
        xcb, wcombT, dtb, BC, b_dt, ML, DI);

    // W_out transpose (after dtG: overlays wcombT)
    transpose_f32_bf16<<<dim3(DM/32, DI/32), 256, 0, stream>>>(W_out, woutT, DI, DM);

    // chunked scan + fused gating (y written over xcb)
    scan_phaseA<<<dim3(DI*4/256, NCHUNK, BB), 256, 0, stream>>>(dtb, xcb, BC, A_log, aprod, hse);
    scan_phaseB<<<(BB*DI*DS)/256, 256, 0, stream>>>(aprod, hse);
    scan_phaseC<<<dim3(DI*4/256, NCHUNK, BB), 256, 0, stream>>>(dtb, xz, BC, A_log, Dvec, hse, xcb);

    // out = y @ W_out  (4096 x 768 x 1536), split-K=3, BK=64 -> d_out,p1,p2
    gemm_bf16<2,3><<<dim3(ML/128, DM/128, 3), 256, 0, stream>>>(
        xcb, woutT, d_out, p1, p2, ML, DM, DI);
    add3<<<(ML*DM)/1024, 256, 0, stream>>>((float*)d_out, p1, p2);

    (void)in_sizes; (void)n_in; (void)out_size; (void)ws_size;
}

// Round 11
// 322.552 us; speedup vs baseline: 1.0217x; 1.0217x over previous
//
#include <hip/hip_runtime.h>
#include <hip/hip_bf16.h>
#include <hip/hip_fp16.h>
#include <math.h>

#define DI 1536
#define DM 768
#define DS 16
#define BB 2
#define LL 2048
#define ML (BB*LL)          /* 4096 rows */
#define NCHUNK 32
#define CLEN (LL/NCHUNK)    /* 64 */
#define NDT 1600            /* dt-GEMM tiled N: 1536 dt + 32 BC + 32 discard */

using short8  = __attribute__((ext_vector_type(8))) short;
using floatx4 = __attribute__((ext_vector_type(4))) float;

__device__ __forceinline__ float bf2f(__hip_bfloat16 v) { return __bfloat162float(v); }

// async global->LDS copy, 16 B per lane (LDS dest lane-contiguous).
__device__ __forceinline__ void async_cp16(const void* g, void* l)
{
    __builtin_amdgcn_global_load_lds(
        (const __attribute__((address_space(1))) unsigned int*)g,
        (__attribute__((address_space(3))) unsigned int*)l,
        16, 0, 0);
}

// ---------------------------------------------------------------------------
__global__ __launch_bounds__(256) void cvt_f32_bf16(
    const float* __restrict__ s, __hip_bfloat16* __restrict__ d)
{
    int i = (blockIdx.x * 256 + threadIdx.x) * 4;
    float4 v = *reinterpret_cast<const float4*>(s + i);
    __hip_bfloat16 o[4];
    o[0] = __float2bfloat16(v.x); o[1] = __float2bfloat16(v.y);
    o[2] = __float2bfloat16(v.z); o[3] = __float2bfloat16(v.w);
    *reinterpret_cast<uint2*>(d + i) = *reinterpret_cast<const uint2*>(o);
}

// ---------------------------------------------------------------------------
// Transpose f32 (R x C) -> bf16 (C x R). Dims multiples of 32.
// ---------------------------------------------------------------------------
__global__ __launch_bounds__(256) void transpose_f32_bf16(
    const float* __restrict__ src, __hip_bfloat16* __restrict__ dst,
    int R, int C)
{
    __shared__ __hip_bfloat16 tile[32][34];
    int c0 = blockIdx.x * 32, r0 = blockIdx.y * 32;
    int lx = threadIdx.x & 31, ly = threadIdx.x >> 5;
#pragma unroll
    for (int i = 0; i < 4; ++i)
        tile[ly + 8*i][lx] = __float2bfloat16(src[(size_t)(r0 + ly + 8*i) * C + c0 + lx]);
    __syncthreads();
#pragma unroll
    for (int i = 0; i < 4; ++i)
        dst[(size_t)(c0 + ly + 8*i) * R + r0 + lx] = tile[lx][ly + 8*i];
}

// ---------------------------------------------------------------------------
// MFMA bf16 GEMM, 128x128 tile, BK=64 as two BK=32 panels (measured win for
// the 128x128 shape, round 9).  B given TRANSPOSED as BT[N,K].
// EPI 0: bf16 -> C0 (stride N).  EPI 2: f32 -> C0/C1/C2 by blockIdx.z.
// ---------------------------------------------------------------------------
template <int EPI, int SK>
__global__ __launch_bounds__(256) void gemm_bf16(
    const __hip_bfloat16* __restrict__ A,
    const __hip_bfloat16* __restrict__ BT,
    void* __restrict__ C0, void* __restrict__ C1, void* __restrict__ C2,
    int M, int N, int K)
{
    __shared__ __hip_bfloat16 As[2][128][32];   // per panel: byte off = tid*16
    __shared__ __hip_bfloat16 Bs[2][128][32];

    int tid  = threadIdx.x;
    int wave = tid >> 6, lane = tid & 63;
    int quad = lane >> 4, lr = lane & 15;
    int wm = (wave >> 1) * 64, wn = (wave & 1) * 64;
    int bm = blockIdx.x * 128, bn = blockIdx.y * 128;

    floatx4 acc[4][4];
#pragma unroll
    for (int i = 0; i < 4; ++i)
#pragma unroll
        for (int j = 0; j < 4; ++j)
            acc[i][j] = (floatx4){0.f, 0.f, 0.f, 0.f};

    int sr = tid >> 2;              // 0..63
    int sc = (tid & 3) * 8;         // 0,8,16,24

    int Klen  = K / SK;
    int kbase = (SK > 1) ? (int)blockIdx.z * Klen : 0;

    const __hip_bfloat16* gA0 = A  + (size_t)(bm + sr)      * K + sc;
    const __hip_bfloat16* gA1 = A  + (size_t)(bm + sr + 64) * K + sc;
    const __hip_bfloat16* gB0 = BT + (size_t)(bn + sr)      * K + sc;
    const __hip_bfloat16* gB1 = BT + (size_t)(bn + sr + 64) * K + sc;

    for (int k0 = kbase; k0 < kbase + Klen; k0 += 64) {
        async_cp16(gA0 + k0,      &As[0][sr][sc]);
        async_cp16(gA0 + k0 + 32, &As[1][sr][sc]);
        async_cp16(gA1 + k0,      &As[0][sr + 64][sc]);
        async_cp16(gA1 + k0 + 32, &As[1][sr + 64][sc]);
        async_cp16(gB0 + k0,      &Bs[0][sr][sc]);
        async_cp16(gB0 + k0 + 32, &Bs[1][sr][sc]);
        async_cp16(gB1 + k0,      &Bs[0][sr + 64][sc]);
        async_cp16(gB1 + k0 + 32, &Bs[1][sr + 64][sc]);
        __syncthreads();

#pragma unroll
        for (int p = 0; p < 2; ++p) {
            short8 afrag[4], bfrag[4];
#pragma unroll
            for (int i = 0; i < 4; ++i)
                afrag[i] = *reinterpret_cast<const short8*>(&As[p][wm + i*16 + lr][quad*8]);
#pragma unroll
            for (int j = 0; j < 4; ++j)
                bfrag[j] = *reinterpret_cast<const short8*>(&Bs[p][wn + j*16 + lr][quad*8]);
#pragma unroll
            for (int i = 0; i < 4; ++i)
#pragma unroll
                for (int j = 0; j < 4; ++j)
                    acc[i][j] = __builtin_amdgcn_mfma_f32_16x16x32_bf16(
                        afrag[i], bfrag[j], acc[i][j], 0, 0, 0);
        }
        __syncthreads();
    }

    float* skOut = nullptr;
    if (EPI == 2)
        skOut = (SK == 1) ? (float*)C0
              : (blockIdx.z == 0 ? (float*)C0 : blockIdx.z == 1 ? (float*)C1 : (float*)C2);

    // epilogue: within 16x16 tile, row = quad*4 + rr, col = lr
#pragma unroll
    for (int i = 0; i < 4; ++i) {
#pragma unroll
        for (int j = 0; j < 4; ++j) {
            int r0 = bm + wm + i*16 + quad*4;
            int c  = bn + wn + j*16 + lr;
#pragma unroll
            for (int rr = 0; rr < 4; ++rr) {
                float v = acc[i][j][rr];
                if (EPI == 0) {
                    ((__hip_bfloat16*)C0)[(size_t)(r0 + rr) * N + c] = __float2bfloat16(v);
                } else {
                    skOut[(size_t)(r0 + rr) * N + c] = v;
                }
            }
        }
    }
}

// ---------------------------------------------------------------------------
// dt-GEMM, 64x64 tile, BK=32: grid 64x25 = 1600 blocks = 6.25/CU for
// latency hiding (round 10: 128x64/800-block version was latency-serialized
// at ~1070 cyc/iter, occupancy-capped by grid).  4 waves per block, wave w
// computes rows [w*16, w*16+16) x 64 cols.  One async_cp16 per thread per
// array per iter.
// B^T = [W_dt^T ; W_x^T ; pad] (NDT x K).  cols<DI: softplus(+bias) -> f16 dt;
// cols DI..DI+31: f32 -> BC; cols >= DI+32: discard.
// ---------------------------------------------------------------------------
__global__ __launch_bounds__(256) void gemm_dt(
    const __hip_bfloat16* __restrict__ A,
    const __hip_bfloat16* __restrict__ BT,
    __half* __restrict__ dtb, float* __restrict__ BC,
    const float* __restrict__ bias,
    int M, int K)
{
    __shared__ __hip_bfloat16 As[64][32];    // 4 KB, byte off = tid*16
    __shared__ __hip_bfloat16 Bs[64][32];    // 4 KB

    int tid  = threadIdx.x;
    int wave = tid >> 6, lane = tid & 63;
    int quad = lane >> 4, lr = lane & 15;
    int wm = wave * 16;
    int bm = blockIdx.x * 64, bn = blockIdx.y * 64;

    floatx4 acc[4];
#pragma unroll
    for (int j = 0; j < 4; ++j)
        acc[j] = (floatx4){0.f, 0.f, 0.f, 0.f};

    int sr = tid >> 2;              // 0..63
    int sc = (tid & 3) * 8;

    const __hip_bfloat16* gA0 = A  + (size_t)(bm + sr) * K + sc;
    const __hip_bfloat16* gB0 = BT + (size_t)(bn + sr) * K + sc;
    __hip_bfloat16* lA0 = &As[sr][sc];
    __hip_bfloat16* lB0 = &Bs[sr][sc];

    for (int k0 = 0; k0 < K; k0 += 32) {
        async_cp16(gA0 + k0, lA0);
        async_cp16(gB0 + k0, lB0);
        __syncthreads();

        short8 afrag, bfrag[4];
        afrag = *reinterpret_cast<const short8*>(&As[wm + lr][quad*8]);
#pragma unroll
        for (int j = 0; j < 4; ++j)
            bfrag[j] = *reinterpret_cast<const short8*>(&Bs[j*16 + lr][quad*8]);
#pragma unroll
        for (int j = 0; j < 4; ++j)
            acc[j] = __builtin_amdgcn_mfma_f32_16x16x32_bf16(
                afrag, bfrag[j], acc[j], 0, 0, 0);
        __syncthreads();
    }

#pragma unroll
    for (int j = 0; j < 4; ++j) {
        int r0 = bm + wm + quad*4;
        int c  = bn + j*16 + lr;
#pragma unroll
        for (int rr = 0; rr < 4; ++rr) {
            float v = acc[j][rr];
            if (c < DI) {
                v += bias[c];
                float sp = (v > 20.f) ? v : log1pf(__expf(v));
                dtb[(size_t)(r0 + rr) * DI + c] = __float2half(sp);
            } else if (c < DI + 32) {
                BC[(size_t)(r0 + rr) * 32 + (c - DI)] = v;
            } // else discard
        }
    }
}

// ---------------------------------------------------------------------------
// d += p1 + p2 (split-K reduce), float4 per thread.
// ---------------------------------------------------------------------------
__global__ __launch_bounds__(256) void add3(
    float* __restrict__ d, const float* __restrict__ p1, const float* __restrict__ p2)
{
    int i = (blockIdx.x * 256 + threadIdx.x) * 4;
    float4 a = *reinterpret_cast<float4*>(d + i);
    float4 b = *reinterpret_cast<const float4*>(p1 + i);
    float4 c = *reinterpret_cast<const float4*>(p2 + i);
    a.x += b.x + c.x; a.y += b.y + c.y; a.z += b.z + c.z; a.w += b.w + c.w;
    *reinterpret_cast<float4*>(d + i) = a;
}

// ---------------------------------------------------------------------------
// Depthwise causal conv (k=4) + bias + SiLU, 4 channels/thread
// (reverted from 8-wide: round-10 total regressed +33 us vs model with the
// 8-wide version as the only non-dtG change).
// ---------------------------------------------------------------------------
__global__ __launch_bounds__(256) void conv_silu(
    const __hip_bfloat16* __restrict__ xz,
    const float* __restrict__ Wc,
    const float* __restrict__ bc,
    __hip_bfloat16* __restrict__ xc)
{
    int idx = blockIdx.x * 256 + threadIdx.x;      // over ML*DI/4
    int d = (idx % (DI/4)) * 4;
    int m = idx / (DI/4);                          // m = b*LL + t
    int t = m % LL;
    float4 b4 = *reinterpret_cast<const float4*>(bc + d);
    float acc[4] = {b4.x, b4.y, b4.z, b4.w};
    float4 w[4];
#pragma unroll
    for (int l = 0; l < 4; ++l)
        w[l] = *reinterpret_cast<const float4*>(Wc + (size_t)(d + l) * 4);
#pragma unroll
    for (int j = 0; j < 4; ++j) {
        if (t - 3 + j >= 0) {
            uint2 raw = *reinterpret_cast<const uint2*>(xz + (size_t)(m - 3 + j) * (2*DI) + d);
            __hip_bfloat16 xv[4];
            *reinterpret_cast<uint2*>(xv) = raw;
#pragma unroll
            for (int l = 0; l < 4; ++l)
                acc[l] += bf2f(xv[l]) * ((const float*)&w[l])[j];
        }
    }
    __hip_bfloat16 o[4];
#pragma unroll
    for (int l = 0; l < 4; ++l) {
        float s = acc[l] / (1.f + __expf(-acc[l]));
        o[l] = __float2bfloat16(s);
    }
    *reinterpret_cast<uint2*>(xc + (size_t)m * DI + d) = *reinterpret_cast<const uint2*>(o);
}

// ---------------------------------------------------------------------------
// Chunked scan, thread-per-(d, 4 states).  32 chunks x 64 steps.
// ---------------------------------------------------------------------------
__global__ __launch_bounds__(256) void scan_phaseA(
    const __half* __restrict__ dt, const __hip_bfloat16* __restrict__ xc,
    const float* __restrict__ BC, const float* __restrict__ A_log,
    __half* __restrict__ aprod, __half* __restrict__ hend)
{
    int idx = blockIdx.x * 256 + threadIdx.x;   // over DI*4 = 6144
    int q = idx & 3, d = idx >> 2;
    int c = blockIdx.y, b = blockIdx.z;
    float A4[4], h[4], ap[4];
#pragma unroll
    for (int j = 0; j < 4; ++j) {
        A4[j] = -__expf(A_log[d*DS + q*4 + j]);
        h[j] = 0.f; ap[j] = 1.f;
    }
    int t0 = c * CLEN;
    for (int t = t0; t < t0 + CLEN; ++t) {
        size_t row = (size_t)b * LL + t;
        float dtv = __half2float(dt[row * DI + d]);
        float xcv = bf2f(xc[row * DI + d]);
        float4 B4 = *reinterpret_cast<const float4*>(BC + row * 32 + q*4);
        float dtx = dtv * xcv;
#pragma unroll
        for (int j = 0; j < 4; ++j) {
            float dA = __expf(dtv * A4[j]);
            h[j]  = dA * h[j] + ((const float*)&B4)[j] * dtx;
            ap[j] *= dA;
        }
    }
    size_t o = (((size_t)b * NCHUNK + c) * DI + d) * DS + q*4;
    __half oa[4], oh[4];
#pragma unroll
    for (int j = 0; j < 4; ++j) { oa[j] = __float2half(ap[j]); oh[j] = __float2half(h[j]); }
    *reinterpret_cast<uint2*>(aprod + o) = *reinterpret_cast<const uint2*>(oa);
    *reinterpret_cast<uint2*>(hend  + o) = *reinterpret_cast<const uint2*>(oh);
}

__global__ __launch_bounds__(256) void scan_phaseB(
    const __half* __restrict__ aprod, __half* __restrict__ hse)
{
    int idx = blockIdx.x * 256 + threadIdx.x;   // over BB*DI*DS
    int b = idx / (DI*DS);
    int dn = idx % (DI*DS);
    float H = 0.f;
#pragma unroll
    for (int c = 0; c < NCHUNK; ++c) {
        size_t o = ((size_t)b * NCHUNK + c) * (DI*DS) + dn;
        float a  = __half2float(aprod[o]);
        float he = __half2float(hse[o]);
        hse[o] = __float2half(H);          // becomes hstart for chunk c
        H = a * H + he;
    }
}

__global__ __launch_bounds__(256) void scan_phaseC(
    const __half* __restrict__ dt, const __hip_bfloat16* __restrict__ xz,
    const float* __restrict__ BC, const float* __restrict__ A_log,
    const float* __restrict__ Dv, const __half* __restrict__ hstart,
    __hip_bfloat16* __restrict__ xc_y /* xc in, y out (in place) */)
{
    int idx = blockIdx.x * 256 + threadIdx.x;   // over DI*4 = 6144
    int q = idx & 3, d = idx >> 2;
    int c = blockIdx.y, b = blockIdx.z;
    float A4[4], h[4];
#pragma unroll
    for (int j = 0; j < 4; ++j)
        A4[j] = -__expf(A_log[d*DS + q*4 + j]);
    float Dd = Dv[d];
    size_t o = (((size_t)b * NCHUNK + c) * DI + d) * DS + q*4;
    {
        uint2 tmp = *reinterpret_cast<const uint2*>(hstart + o);
        const __half* hp = reinterpret_cast<const __half*>(&tmp);
#pragma unroll
        for (int j = 0; j < 4; ++j) h[j] = __half2float(hp[j]);
    }
    int t0 = c * CLEN;
    for (int t = t0; t < t0 + CLEN; ++t) {
        size_t row = (size_t)b * LL + t;
        float dtv = __half2float(dt[row * DI + d]);
        float xcv = bf2f(xc_y[row * DI + d]);       // read BEFORE the masked write
        float zv  = bf2f(xz[row * (2*DI) + DI + d]);
        float4 B4 = *reinterpret_cast<const float4*>(BC + row * 32 + q*4);
        float4 C4 = *reinterpret_cast<const float4*>(BC + row * 32 + 16 + q*4);
        float dtx = dtv * xcv;
        float ys = 0.f;
#pragma unroll
        for (int j = 0; j < 4; ++j) {
            float dA = __expf(dtv * A4[j]);
            h[j] = dA * h[j] + ((const float*)&B4)[j] * dtx;
            ys = fmaf(h[j], ((const float*)&C4)[j], ys);
        }
        ys += __shfl_xor(ys, 1);
        ys += __shfl_xor(ys, 2);
        if (q == 0) {
            float sig = 1.f / (1.f + __expf(-zv));
            float out = (ys + xcv * Dd) * (zv * sig);
            xc_y[row * DI + d] = __float2bfloat16(out);
        }
    }
}

// ---------------------------------------------------------------------------
extern "C" void kernel_launch(void* const* d_in, const int* in_sizes, int n_in,
                              void* d_out, int out_size, void* d_ws, size_t ws_size,
                              hipStream_t stream)
{
    const float* x      = (const float*)d_in[0];
    const float* W_in   = (const float*)d_in[1];
    const float* W_conv = (const float*)d_in[2];
    const float* b_conv = (const float*)d_in[3];
    const float* W_x    = (const float*)d_in[4];
    const float* W_dt   = (const float*)d_in[5];
    const float* b_dt   = (const float*)d_in[6];
    const float* A_log  = (const float*)d_in[7];
    const float* Dvec   = (const float*)d_in[8];
    const float* W_out  = (const float*)d_in[9];

    // ---- workspace layout (62.26 MiB, explicit lifetime reuse) ----
    uint8_t* ws = (uint8_t*)d_ws;
    __hip_bfloat16* xz     = (__hip_bfloat16*)(ws);               // 25,165,824 [G1..phaseC]
    float*          p1     = (float*)(ws);                        // 12,582,912 [G4..add3] (over xz)
    float*          p2     = (float*)(ws + 12582912);             // 12,582,912 [G4..add3] (over xz)
    __hip_bfloat16* winT   = (__hip_bfloat16*)(ws + 25165824);    //  4,718,592 [T1..G1]
    __half*         aprod  = (__half*)(ws + 25165824);            //  3,145,728 [phA..phB] (over winT)
    __half*         hse    = (__half*)(ws + 28311552);            //  3,145,728 [phA..phC] (over winT)
    __hip_bfloat16* wcombT = (__hip_bfloat16*)(ws + 31457280);    //  4,915,200 [T2..dtG]  (NDT x DI; rows 1568+ unwritten)
    __hip_bfloat16* woutT  = (__hip_bfloat16*)(ws + 31457280);    //  2,359,296 [T3..G4]   (over wcombT, after dtG)
    __hip_bfloat16* xcb    = (__hip_bfloat16*)(ws + 36569088);    // 12,582,912 [conv..G4], y in place
    __half*         dtb    = (__half*)(ws + 49152000);            // 12,582,912 [dtG..phaseC]
    __hip_bfloat16* xbf    = (__hip_bfloat16*)(ws + 49152000);    //  6,291,456 [cvt..G1]  (over dtb)
    float*          BC     = (float*)(ws + 61734912);             //    524,288 [dtG..phaseC]
    // end: 62,259,200 bytes

    // input conversions / weight transposes (f32 -> bf16, B^T layout)
    cvt_f32_bf16<<<(ML*DM)/1024, 256, 0, stream>>>(x, xbf);
    transpose_f32_bf16<<<dim3(2*DI/32, DM/32), 256, 0, stream>>>(W_in, winT, DM, 2*DI);
    transpose_f32_bf16<<<dim3(DI/32,   DI/32), 256, 0, stream>>>(W_dt, wcombT, DI, DI);
    transpose_f32_bf16<<<dim3(1,       DI/32), 256, 0, stream>>>(W_x,  wcombT + (size_t)DI*DI, DI, 32);

    // GEMM1: xz = x @ W_in     (4096 x 3072 x 768), BK=64
    gemm_bf16<0,1><<<dim3(ML/128, (2*DI)/128), 256, 0, stream>>>(
        xbf, winT, xz, nullptr, nullptr, ML, 2*DI, DM);

    // conv + SiLU -> xc
    conv_silu<<<(ML*DI/4)/256, 256, 0, stream>>>(xz, W_conv, b_conv, xcb);

    // fused: dt = softplus(xc @ W_dt + b_dt) -> f16  AND  BC = xc @ W_x -> f32
    // 64x64 tile, BK=32: 1600 blocks = 6.25/CU
    gemm_dt<<<dim3(ML/64, NDT/64), 256, 0, stream>>>(
        xcb, wcombT, dtb, BC, b_dt, ML, DI);

    // W_out transpose (after dtG: overlays wcombT)
    transpose_f32_bf16<<<dim3(DM/32, DI/32), 256, 0, stream>>>(W_out, woutT, DI, DM);

    // chunked scan + fused gating (y written over xcb)
    scan_phaseA<<<dim3(DI*4/256, NCHUNK, BB), 256, 0, stream>>>(dtb, xcb, BC, A_log, aprod, hse);
    scan_phaseB<<<(BB*DI*DS)/256, 256, 0, stream>>>(aprod, hse);
    scan_phaseC<<<dim3(DI*4/256, NCHUNK, BB), 256, 0, stream>>>(dtb, xz, BC, A_log, Dvec, hse, xcb);

    // out = y @ W_out  (4096 x 768 x 1536), split-K=3, BK=64 -> d_out,p1,p2
    gemm_bf16<2,3><<<dim3(ML/128, DM/128, 3), 256, 0, stream>>>(
        xcb, woutT, d_out, p1, p2, ML, DM, DI);
    add3<<<(ML*DM)/1024, 256, 0, stream>>>((float*)d_out, p1, p2);

    (void)in_sizes; (void)n_in; (void)out_size; (void)ws_size;
}